// Round 12
// baseline (121.930 us; speedup 1.0000x reference)
//
#include <hip/hip_runtime.h>
#include <hip/hip_bf16.h>

// DigitCaps, fp32 in / fp32 out:
//   u [16,1152,8], W [10,1152,16,8], Bp [10,1,1152], out [16,10,16]
// Exact algebra: A_sum[b,d,m] = dot(T[b,d,:], U_hat[b,d,m,:])/sqrt8,
//   T = sum_n U_hat;  C = softmax_d;  S = sum_n (Bp+C)*U_hat;  squash(S).
// Round-11 lesson: hipLaunchCooperativeKernel silently fails under this
// harness (all-zero output) -> no grid.sync available. Round 12: 2 compute
// kernels + tiny memset; reductions via 4-way-split atomicAdd (144 RMW/addr);
// squash fused into caps_S's last-arriving block (fence+counter, no spin,
// deadlock-free). ws traffic drops 36 MB -> 80 KB vs round 10.
constexpr int BN = 16, NN = 1152, DP = 8, ND = 10, DD = 16;
constexpr int NCH = 2;                   // n's per block
constexpr int NBLK = NN / NCH;           // 576 blocks
constexpr int CELLS = BN * ND * DD;      // 2560; cell = d*256 + b*16 + j
constexpr int SPLIT = 4;                 // contention splits

__device__ __forceinline__ void load8(const float* __restrict__ p, float* dst) {
    const float4 a = reinterpret_cast<const float4*>(p)[0];
    const float4 b = reinterpret_cast<const float4*>(p)[1];
    dst[0] = a.x; dst[1] = a.y; dst[2] = a.z; dst[3] = a.w;
    dst[4] = b.x; dst[5] = b.y; dst[6] = b.z; dst[7] = b.w;
}

// ---- K1: partial T, atomic into 4-way-split accumulator ----
__global__ __launch_bounds__(256) void caps_T(
    const float* __restrict__ u, const float* __restrict__ W,
    float* __restrict__ Tsp)
{
    const int t = threadIdx.x, j = t & 15, b = t >> 4;
    const int n0 = blockIdx.x * NCH;
    float Tacc[ND];
#pragma unroll
    for (int d = 0; d < ND; ++d) Tacc[d] = 0.f;

    for (int nn = 0; nn < NCH; ++nn) {
        const int n = n0 + nn;
        float uf[DP];
        load8(u + ((size_t)b * NN + n) * DP, uf);
#pragma unroll
        for (int d = 0; d < ND; ++d) {           // 10 independent load8s
            float wf[DP];
            load8(W + (((size_t)d * NN + n) * DD + j) * DP, wf);
            float s = 0.f;
#pragma unroll
            for (int i = 0; i < DP; ++i) s += wf[i] * uf[i];
            Tacc[d] += s;
        }
    }
    float* Tdst = Tsp + (size_t)(blockIdx.x & (SPLIT - 1)) * CELLS;
#pragma unroll
    for (int d = 0; d < ND; ++d)
        atomicAdd(&Tdst[d * 256 + t], Tacc[d]);  // 144 RMWs per address
}

// ---- K2: scores -> softmax_d -> S (split atomics); last block squashes ----
__global__ __launch_bounds__(256) void caps_S(
    const float* __restrict__ u, const float* __restrict__ W,
    const float* __restrict__ Bp, const float* __restrict__ Tsp,
    float* __restrict__ Ssp, unsigned* __restrict__ counter,
    float* __restrict__ out)
{
    __shared__ unsigned ticket_s;
    const int t = threadIdx.x, j = t & 15, b = t >> 4;
    constexpr float RS8 = 0.35355339059327373f;  // 1/sqrt(8)

    float Treg[ND];                               // sum the 4 splits (L2-hot)
#pragma unroll
    for (int q = 0; q < ND; ++q) {
        float s = 0.f;
#pragma unroll
        for (int p = 0; p < SPLIT; ++p) s += Tsp[(size_t)p * CELLS + q * 256 + t];
        Treg[q] = s;
    }

    float Sacc[ND];
#pragma unroll
    for (int q = 0; q < ND; ++q) Sacc[q] = 0.f;

    const int n0 = blockIdx.x * NCH;
    for (int nn = 0; nn < NCH; ++nn) {
        const int n = n0 + nn;
        float uf[DP];
        load8(u + ((size_t)b * NN + n) * DP, uf);
        float uh[ND], a[ND];
#pragma unroll
        for (int q = 0; q < ND; ++q) {            // 10 independent load8s
            float wf[DP];
            load8(W + (((size_t)q * NN + n) * DD + j) * DP, wf);
            float s = 0.f;
#pragma unroll
            for (int i = 0; i < DP; ++i) s += wf[i] * uf[i];
            uh[q] = s;
            float v = Treg[q] * s;                // butterfly over 16 j-lanes
            v += __shfl_xor(v, 8, 16);
            v += __shfl_xor(v, 4, 16);
            v += __shfl_xor(v, 2, 16);
            v += __shfl_xor(v, 1, 16);
            a[q] = v * RS8;
        }
        float m = a[0];
#pragma unroll
        for (int q = 1; q < ND; ++q) m = fmaxf(m, a[q]);
        float e[ND], se = 0.f;
#pragma unroll
        for (int q = 0; q < ND; ++q) { e[q] = expf(a[q] - m); se += e[q]; }
        const float inv_se = 1.f / se;
#pragma unroll
        for (int q = 0; q < ND; ++q)
            Sacc[q] += (Bp[q * NN + n] + e[q] * inv_se) * uh[q];
    }
    float* Sdst = Ssp + (size_t)(blockIdx.x & (SPLIT - 1)) * CELLS;
#pragma unroll
    for (int q = 0; q < ND; ++q)
        atomicAdd(&Sdst[q * 256 + t], Sacc[q]);   // 144 RMWs per address

    // ---- last-arriving block: squash + output (no spin, no extra kernel) ----
    __threadfence();                              // release our S-adds
    if (t == 0) ticket_s = atomicAdd(counter, 1u);
    __syncthreads();
    if (ticket_s == NBLK - 1) {                   // every other block released
        __threadfence();                          // acquire
#pragma unroll
        for (int d = 0; d < ND; ++d) {            // cell = d*256 + (b*16+j)
            float Sv = 0.f;
#pragma unroll
            for (int p = 0; p < SPLIT; ++p)       // device-scope atomic reads
                Sv += atomicAdd(&Ssp[(size_t)p * CELLS + d * 256 + t], 0.f);
            float n2 = Sv * Sv;
#pragma unroll
            for (int off = 8; off >= 1; off >>= 1)
                n2 += __shfl_xor(n2, off, 16);
            const float nrm = sqrtf(n2);
            const float coef = 1.f - 1.f / (expf(nrm) + 1e-7f);
            out[((size_t)b * ND + d) * DD + j] = Sv * (coef / (nrm + 1e-7f));
        }
    }
}

extern "C" void kernel_launch(void* const* d_in, const int* in_sizes, int n_in,
                              void* d_out, int out_size, void* d_ws, size_t ws_size,
                              hipStream_t stream) {
    const float* u  = nullptr;   // 147456
    const float* W  = nullptr;   // 1474560
    const float* Bp = nullptr;   // 11520
    for (int i = 0; i < n_in; ++i) {
        const int s = in_sizes[i];
        if (s == BN * NN * DP)            u  = (const float*)d_in[i];
        else if (s == ND * NN * DD * DP)  W  = (const float*)d_in[i];
        else if (s == ND * NN)            Bp = (const float*)d_in[i];
    }
    float* out = (float*)d_out;
    float* Tsp = (float*)d_ws;                    // 4*2560 fp32
    float* Ssp = Tsp + (size_t)SPLIT * CELLS;     // 4*2560 fp32
    unsigned* counter = (unsigned*)(Ssp + (size_t)SPLIT * CELLS);

    // zero T/S accumulators + counter (82 KB fill, graph-capturable)
    hipMemsetAsync(d_ws, 0,
                   (2 * SPLIT * CELLS) * sizeof(float) + sizeof(unsigned),
                   stream);
    caps_T<<<dim3(NBLK), 256, 0, stream>>>(u, W, Tsp);
    caps_S<<<dim3(NBLK), 256, 0, stream>>>(u, W, Bp, Tsp, Ssp, counter, out);
}

// Round 13
// 83.029 us; speedup vs baseline: 1.4685x; 1.4685x over previous
//
#include <hip/hip_runtime.h>
#include <hip/hip_bf16.h>

// DigitCaps, fp32 in / fp32 out:
//   u [16,1152,8], W [10,1152,16,8], Bp [10,1,1152], out [16,10,16]
// Exact algebra: A_sum[b,d,m] = dot(T[b,d,:], U_hat[b,d,m,:])/sqrt8,
//   T = sum_n U_hat;  C = softmax_d;  S = sum_n (Bp+C)*U_hat;  squash(S).
// Round-12 lessons: (1) fp32 atomicAdd is EA-side write-through (WRITE_SIZE
// 5.8 MB = atomic count x 4B) -> atomic-free only. (2) VGPR=76 forced the
// compiler to serialize the 20 load8s into dozens of HBM round trips per
// block (VALUBusy 6%, 197 GB/s). Round 13: cooperative LDS staging — all
// of a block's W/u/T staged with ~3 independent loads/thread, ONE vmcnt
// wait, then LDS-only compute. Atomic-free partials + R10 reduce kernels.
constexpr int BN = 16, NN = 1152, DP = 8, ND = 10, DD = 16;
constexpr int NCH = 2;                   // n's per phase block
constexpr int NBLK = NN / NCH;           // 576 blocks
constexpr int CELLS = BN * ND * DD;      // 2560; cell = d*256 + b*16 + j
constexpr int RL = 16;                   // reduction lanes per cell
constexpr int WCH = NCH * ND;            // 20 staged W chunks (512 B each)

// ---- Phase A: stage W/u in LDS, compute partial T, streaming stores ----
__global__ __launch_bounds__(256) void caps_T(
    const float* __restrict__ u, const float* __restrict__ W,
    float* __restrict__ Tp)
{
    __shared__ float Wl[WCH * 128];      // 20 chunks x 128 floats = 10 KB
    __shared__ float ul[BN * NCH * DP];  // 256 floats = 1 KB
    const int t = threadIdx.x;
    const int n0 = blockIdx.x * NCH;

    // stage W: 640 float4, coalesced, all independent (one vmcnt wait)
    for (int g = t; g < WCH * 32; g += 256) {
        const int c = g >> 5, w = g & 31;           // chunk, float4-in-chunk
        const int nn = c / ND, d = c - nn * ND;
        reinterpret_cast<float4*>(Wl)[g] =
            *reinterpret_cast<const float4*>(
                W + ((size_t)d * NN + (n0 + nn)) * (DD * DP) + w * 4);
    }
    // stage u: 64 float4
    if (t < BN * NCH * 2) {
        const int b = t >> 2, r = t & 3, nn = r >> 1, half = r & 1;
        reinterpret_cast<float4*>(ul)[t] =
            *reinterpret_cast<const float4*>(
                u + ((size_t)b * NN + (n0 + nn)) * DP + half * 4);
    }
    __syncthreads();

    const int j = t & 15, b = t >> 4;
    float Tacc[ND];
#pragma unroll
    for (int d = 0; d < ND; ++d) Tacc[d] = 0.f;

#pragma unroll
    for (int nn = 0; nn < NCH; ++nn) {
        const float4 u0 = reinterpret_cast<const float4*>(ul)[b * 4 + nn * 2];
        const float4 u1 = reinterpret_cast<const float4*>(ul)[b * 4 + nn * 2 + 1];
#pragma unroll
        for (int d = 0; d < ND; ++d) {
            const float4* wp =
                reinterpret_cast<const float4*>(Wl) + (nn * ND + d) * 32 + j * 2;
            const float4 w0 = wp[0], w1 = wp[1];
            Tacc[d] += w0.x * u0.x + w0.y * u0.y + w0.z * u0.z + w0.w * u0.w
                     + w1.x * u1.x + w1.y * u1.y + w1.z * u1.z + w1.w * u1.w;
        }
    }
    float* dst = Tp + (size_t)blockIdx.x * CELLS;
#pragma unroll
    for (int d = 0; d < ND; ++d) dst[d * 256 + t] = Tacc[d];   // 1 KB runs
}

// ---- reduce Tp[576][2560] -> T[2560]: 160 blocks, 16 lanes/cell ----
__global__ __launch_bounds__(256) void reduce_T(
    const float* __restrict__ Tp, float* __restrict__ T)
{
    __shared__ float red[256];
    const int t = threadIdx.x;
    const int cell = blockIdx.x * RL + (t & 15);
    const int cc = t >> 4;
    float s = 0.f;
    for (int k = 0; k < NBLK / RL; ++k)            // 36 chained loads
        s += Tp[(size_t)(cc + RL * k) * CELLS + cell];
    red[t] = s;
    __syncthreads();
    if (t < RL) {
        float acc = 0.f;
#pragma unroll
        for (int g = 0; g < RL; ++g) acc += red[t + RL * g];
        T[blockIdx.x * RL + t] = acc;
    }
}

// ---- Phase B: stage W/u/T, scores -> softmax_d -> partial S ----
__global__ __launch_bounds__(256) void caps_S(
    const float* __restrict__ u, const float* __restrict__ W,
    const float* __restrict__ Bp, const float* __restrict__ T,
    float* __restrict__ Sp)
{
    __shared__ float Wl[WCH * 128];      // 10 KB
    __shared__ float ul[BN * NCH * DP];  // 1 KB
    __shared__ float Tl[CELLS];          // 10 KB
    const int t = threadIdx.x;
    const int n0 = blockIdx.x * NCH;
    constexpr float RS8 = 0.35355339059327373f;    // 1/sqrt(8)

    for (int g = t; g < WCH * 32; g += 256) {
        const int c = g >> 5, w = g & 31;
        const int nn = c / ND, d = c - nn * ND;
        reinterpret_cast<float4*>(Wl)[g] =
            *reinterpret_cast<const float4*>(
                W + ((size_t)d * NN + (n0 + nn)) * (DD * DP) + w * 4);
    }
    for (int g = t; g < CELLS / 4; g += 256)       // T: 640 float4 linear copy
        reinterpret_cast<float4*>(Tl)[g] = reinterpret_cast<const float4*>(T)[g];
    if (t < BN * NCH * 2) {
        const int b = t >> 2, r = t & 3, nn = r >> 1, half = r & 1;
        reinterpret_cast<float4*>(ul)[t] =
            *reinterpret_cast<const float4*>(
                u + ((size_t)b * NN + (n0 + nn)) * DP + half * 4);
    }
    __syncthreads();

    const int j = t & 15, b = t >> 4;
    float Treg[ND];
#pragma unroll
    for (int q = 0; q < ND; ++q) Treg[q] = Tl[q * 256 + t];  // conflict-free

    float Sacc[ND];
#pragma unroll
    for (int q = 0; q < ND; ++q) Sacc[q] = 0.f;

#pragma unroll
    for (int nn = 0; nn < NCH; ++nn) {
        const int n = n0 + nn;
        const float4 u0 = reinterpret_cast<const float4*>(ul)[b * 4 + nn * 2];
        const float4 u1 = reinterpret_cast<const float4*>(ul)[b * 4 + nn * 2 + 1];
        float uh[ND], a[ND];
#pragma unroll
        for (int q = 0; q < ND; ++q) {
            const float4* wp =
                reinterpret_cast<const float4*>(Wl) + (nn * ND + q) * 32 + j * 2;
            const float4 w0 = wp[0], w1 = wp[1];
            const float s =
                  w0.x * u0.x + w0.y * u0.y + w0.z * u0.z + w0.w * u0.w
                + w1.x * u1.x + w1.y * u1.y + w1.z * u1.z + w1.w * u1.w;
            uh[q] = s;
            float v = Treg[q] * s;                 // butterfly over 16 j-lanes
            v += __shfl_xor(v, 8, 16);
            v += __shfl_xor(v, 4, 16);
            v += __shfl_xor(v, 2, 16);
            v += __shfl_xor(v, 1, 16);
            a[q] = v * RS8;
        }
        float m = a[0];
#pragma unroll
        for (int q = 1; q < ND; ++q) m = fmaxf(m, a[q]);
        float e[ND], se = 0.f;
#pragma unroll
        for (int q = 0; q < ND; ++q) { e[q] = expf(a[q] - m); se += e[q]; }
        const float inv_se = 1.f / se;
#pragma unroll
        for (int q = 0; q < ND; ++q)
            Sacc[q] += (Bp[q * NN + n] + e[q] * inv_se) * uh[q];
    }
    float* dst = Sp + (size_t)blockIdx.x * CELLS;
#pragma unroll
    for (int q = 0; q < ND; ++q) dst[q * 256 + t] = Sacc[q];
}

// ---- reduce Sp[576][2560] + fused squash: 160 blocks = (q,b) ----
__global__ __launch_bounds__(256) void reduce_S_out(
    const float* __restrict__ Sp, float* __restrict__ out)
{
    __shared__ float red[256];
    const int q = blockIdx.x >> 4, b = blockIdx.x & 15;
    const int t = threadIdx.x, j = t & 15, cc = t >> 4;
    const int cell = q * 256 + b * 16 + j;
    float s = 0.f;
    for (int k = 0; k < NBLK / RL; ++k)            // 36 chained loads
        s += Sp[(size_t)(cc + RL * k) * CELLS + cell];
    red[t] = s;
    __syncthreads();
    if (t < RL) {                                  // t = j
        float Sv = 0.f;
#pragma unroll
        for (int g = 0; g < RL; ++g) Sv += red[t + RL * g];
        float n2 = Sv * Sv;
#pragma unroll
        for (int off = 8; off >= 1; off >>= 1) n2 += __shfl_xor(n2, off, 16);
        const float nrm = sqrtf(n2);
        const float coef = 1.f - 1.f / (expf(nrm) + 1e-7f);
        out[((size_t)b * ND + q) * DD + t] = Sv * (coef / (nrm + 1e-7f));
    }
}

extern "C" void kernel_launch(void* const* d_in, const int* in_sizes, int n_in,
                              void* d_out, int out_size, void* d_ws, size_t ws_size,
                              hipStream_t stream) {
    const float* u  = nullptr;   // 147456
    const float* W  = nullptr;   // 1474560
    const float* Bp = nullptr;   // 11520
    for (int i = 0; i < n_in; ++i) {
        const int s = in_sizes[i];
        if (s == BN * NN * DP)            u  = (const float*)d_in[i];
        else if (s == ND * NN * DD * DP)  W  = (const float*)d_in[i];
        else if (s == ND * NN)            Bp = (const float*)d_in[i];
    }
    float* out = (float*)d_out;
    float* Tp = (float*)d_ws;                     // 576*2560 fp32 = 5.9 MB
    float* T  = Tp + (size_t)NBLK * CELLS;        // 2560 fp32
    float* Sp = T + CELLS;                        // 576*2560 fp32 = 5.9 MB
    // every ws word is written before read -> poison harmless; no memset

    caps_T      <<<dim3(NBLK), 256, 0, stream>>>(u, W, Tp);
    reduce_T    <<<dim3(CELLS / RL), 256, 0, stream>>>(Tp, T);
    caps_S      <<<dim3(NBLK), 256, 0, stream>>>(u, W, Bp, T, Sp);
    reduce_S_out<<<dim3(ND * BN), 256, 0, stream>>>(Sp, out);
}